// Round 12
// baseline (812.508 us; speedup 1.0000x reference)
//
#include <hip/hip_runtime.h>

// FSMN depthwise strided FIR — R12: persistent segment blocks.
// B=32, T=2000, D=512, L=R=20, stride 2.
//
// R11 post-mortem: 512-thread blocks cap VGPR at 128 on this toolchain
// REGARDLESS of launch_bounds arg2 (R10 lb(512,2) and R11 lb(512,1) both
// pinned 128 + wholesale spill). 8-wave blocks are unusable for this
// ~200-VGPR body. Only proven-clean shape: 256 thr + lb(256,1) (R7).
//
// R7 cost model: 19k cy/block = exposed 89KB prologue DMA (~8k) + phase
// drains + ~6k LDS-pipe + 2.6k fmac. R12 removes the prologue from the
// steady state: each block persists over 16 consecutive 16-m tiles of one
// (b, d-half, 256-m segment). The 112-row window slides 32 rows/tile, so
// per tile only 32 NEW rows are staged (halo lives in the ring) — 3.5x
// less DMA than R7 — issued mid-tile and covered by 29 steps of compute.
//
// LDS (153 KB): full filt [41 rows][1KB] at FOFF (per-step ds_read with
// compile-time imm offset, dist-2 reg queue) + x ring of XR=112 rows
// (slot = br mod 112; one conditional subtract, wave-uniform).
// Tile k frame: rel row r in [0,111] = abs x row R0k + r, R0k = R00+32k.
// slot(rel r) = wrap(tbm + r), tbm = 32k mod 112.
// Liveness (verified): staged slots = wrap(tbm+0..31) (rel rows 112..143
// = next tile's 80..111). Rel rows 0..31 last LDS-read: push at
// t=(r-8mg-8)/2 <= 11 (mg=0, r=31). Steps >=12 read rel >= 32. So:
//   [init windows; steps 0..11] BARRIER [stage 32 rows (8/wave)]
//   [steps 12..40; guarded stores] BARRIER (drains DMA; next tile reads)
// Prologue (once per block): filt 41 rows + tile-0 rel 0..111.
// All bounds handled at staging (OOB -> zero rows); compute checkless;
// stores guarded by m < S_. No early returns; all waves hit all barriers.
//
// Step semantics (refcheck'd R4..R11): t<=20: ae+=f[t]*wE, ao+=f[t]*wO;
// t>=21 swapped. E push rel=8mg+2t+8; O push +1 (t<20) / -1 (t>20);
// O holds at t=20. Runtime k-loop is rule-#20-safe: every float4 array
// indexed only by compile-time m/t; runtime state is scalar (tbm, m0k).
//
// Spill ledger: 256thr+lb(256,1) -> natural 256, clean x3 (R7/R9/R11-
// compile). 512thr -> 128 pin, spill x2. R12: 256thr, lb(256,1).

#define B_ 32
#define T_ 2000
#define D_ 512
#define S_ 1000   // T/2
#define M_ 4      // m per thread
#define TM 16     // m per tile (4 waves x M_)
#define TILES 16  // tiles per segment
#define SEGM (TM * TILES)   // 256 m per segment
#define XR 112    // x ring rows
#define FOFF 0
#define XOFF (41 * 256)
#define LDS_FLOATS (XOFF + XR * 256)   // 153 rows = 156672 B

__device__ __forceinline__ float4 zf4() {
    float4 z; z.x = 0.f; z.y = 0.f; z.z = 0.f; z.w = 0.f; return z;
}

__device__ __forceinline__ void fma4(float4& a, const float4 f, const float4 w) {
    a.x = fmaf(f.x, w.x, a.x);
    a.y = fmaf(f.y, w.y, a.y);
    a.z = fmaf(f.z, w.z, a.z);
    a.w = fmaf(f.w, w.w, a.w);
}

// Async global->LDS DMA: 16B/lane x 64 lanes = one 1KB row per call.
__device__ __forceinline__ void gload_lds16(const float* g, float* l) {
    __builtin_amdgcn_global_load_lds(
        (const __attribute__((address_space(1))) void*)g,
        (__attribute__((address_space(3))) void*)l,
        16, 0, 0);
}

__global__ __launch_bounds__(256, 1) void fsmn_kernel(
    const float* __restrict__ x, const float* __restrict__ filt,
    float* __restrict__ out)
{
    __shared__ float lds[LDS_FLOATS];      // 153 KB

    const int lane = threadIdx.x;          // 0..63
    const int mg   = threadIdx.y;          // 0..3 : wave id

    // 256 blocks = 8 XCDs x 32 (one per CU). seg fastest within XCD chunk.
    const int bid  = blockIdx.x;
    const int n    = (bid & 7) * 32 + (bid >> 3);   // 0..255
    const int seg  = n & 3;                // 0..3 : 256-m segment
    const int dh   = (n >> 2) & 1;         // d-half
    const int b    = n >> 3;               // batch

    const int m0seg = seg * SEGM;
    const int d  = (dh * 64 + lane) * 4;
    const float* xb = x + (size_t)b * T_ * D_ + d;
    const float* fb = filt + d;
    float*       ob = out + (size_t)b * T_ * D_ + d;
    const int R00 = 2 * m0seg - 40;        // abs x row of segment rel-row 0

    // slot in [0, XR): writes/reads x ring row
    auto stageRow = [&](int absrow, int slot) {
        float* l = lds + XOFF + (slot << 8);
        if ((unsigned)absrow < (unsigned)T_) {
            gload_lds16(xb + (size_t)absrow * D_, l);   // xb already + lane*4
        } else {
            *(float4*)(l + lane * 4) = zf4();           // zero-fill pad rows
        }
    };
    auto ldslot = [&](int slot) -> float4 {
        return *(const float4*)(lds + XOFF + (slot << 8) + lane * 4);
    };
    auto ldsF = [&](int t) -> float4 {     // t compile-time -> imm offset
        return *(const float4*)(lds + FOFF + (t << 8) + lane * 4);
    };
    auto wrap = [](int s) { return s >= XR ? s - XR : s; };   // s < 2*XR

    // ---- Prologue (once per block): filt rows 0..40 + x rel rows 0..111 ----
#pragma unroll
    for (int i = 0; i < 11; ++i) {
        const int fr = 4 * i + mg;
        if (fr <= 40) gload_lds16(fb + (size_t)fr * D_, lds + FOFF + (fr << 8));
    }
#pragma unroll
    for (int i = 0; i < 28; ++i) {
        const int r = 4 * i + mg;          // 0..111, slot == r
        stageRow(R00 + r, r);
    }
    __syncthreads();

    // ---- Persistent tile loop ----
    int tbm = 0;                           // (32k) mod 112
    int m0k = m0seg;                       // tile's first m
#pragma unroll 1
    for (int k = 0; k < TILES; ++k) {
        const int wb  = tbm + 8 * mg;      // wave slot base (<=120)
        const int m0w = m0k + M_ * mg;     // wave's first m

        float4 wE[M_], wO[M_], ae[M_], ao[M_];
#pragma unroll
        for (int m = 0; m < M_; ++m) {
            wE[m] = ldslot(wrap(wb + 2 * m));
            wO[m] = ldslot(wrap(wb + 2 * m + 1));
            ae[m] = zf4(); ao[m] = zf4();
        }
        float4 qF0 = ldsF(0), qF1 = ldsF(1);

        auto dostep = [&](int t) {         // t compile-time under unroll
            const float4 fv = qF0;
            qF0 = qF1;
            qF1 = (t + 2 <= 40) ? ldsF(t + 2) : zf4();
            if (t <= 20) {
#pragma unroll
                for (int m = 0; m < M_; ++m) { fma4(ae[m], fv, wE[m]); fma4(ao[m], fv, wO[m]); }
            } else {
#pragma unroll
                for (int m = 0; m < M_; ++m) { fma4(ao[m], fv, wE[m]); fma4(ae[m], fv, wO[m]); }
            }
            if (t < 40) {
#pragma unroll
                for (int m = 0; m < M_ - 1; ++m) wE[m] = wE[m + 1];
                wE[M_ - 1] = ldslot(wrap(wb + 2 * t + 8));
                if (t != 20) {             // O holds at the junction
#pragma unroll
                    for (int m = 0; m < M_ - 1; ++m) wO[m] = wO[m + 1];
                    wO[M_ - 1] = ldslot(wrap(wb + 2 * t + 8 + ((t < 20) ? 1 : -1)));
                }
            }
        };

#pragma unroll
        for (int t = 0; t < 12; ++t) dostep(t);
        __syncthreads();                   // rel rows 0..31 now dead everywhere

        if (k < TILES - 1) {               // stage next tile's 32 new rows
            const int absbase = R00 + 32 * k + 112 + 8 * mg;
#pragma unroll
            for (int i = 0; i < 8; ++i) stageRow(absbase + i, wrap(wb + i));
        }

#pragma unroll
        for (int t = 12; t <= 40; ++t) dostep(t);

        // guarded stores (8 rows per thread)
#pragma unroll
        for (int m = 0; m < M_; ++m) {
            if (m0w + m < S_) {
                *(float4*)(ob + (size_t)(2 * (m0w + m))     * D_) = ae[m];
                *(float4*)(ob + (size_t)(2 * (m0w + m) + 1) * D_) = ao[m];
            }
        }
        __syncthreads();                   // drain DMA; fence next tile reads

        tbm += 32; if (tbm >= XR) tbm -= XR;
        m0k += TM;
    }
}

extern "C" void kernel_launch(void* const* d_in, const int* in_sizes, int n_in,
                              void* d_out, int out_size, void* d_ws, size_t ws_size,
                              hipStream_t stream) {
    const float* x    = (const float*)d_in[0];
    const float* filt = (const float*)d_in[1];
    float*       out  = (float*)d_out;

    dim3 block(64, 4, 1);
    // 32 batches x 2 d-halves x 4 segments = 256 persistent blocks (1/CU).
    dim3 grid(256, 1, 1);
    hipLaunchKernelGGL(fsmn_kernel, grid, block, 0, stream, x, filt, out);
}

// Round 13
// 591.977 us; speedup vs baseline: 1.3725x; 1.3725x over previous
//
#include <hip/hip_runtime.h>

// FSMN depthwise strided FIR — R13: R9 geometry + running-pointer staging
// + lb(256,2) for true 2-blocks/CU co-residency.
// B=32, T=2000, D=512, L=R=20, stride 2.
//
// R12 post-mortem: runtime ring base (loop-carried tbm + cmp-sub wrap)
// => scheduler hoists ~62 address computations across the unrolled tile,
// live set > 256, wholesale spill (1.1GB FETCH). Ring indices must be
// compile-time-foldable: pow2-AND of per-step constants (R7/R9 style).
//
// Co-residency condition (from R9+m69): VGPR<=128 AND LDS<=80KB. R9 had
// the LDS (76KB) but VGPR=256 caps the CU at 4 waves -> 1 block/CU.
// R8 tried cap-128 and spilled on per-phase index recompute/hoisting.
// R13 removes that pressure: staging addresses are RUNNING POINTERS
// advanced += const per phase (2 regs each), not recomputed from p.
//
// Geometry (identical to R9, verified absmax 0.125):
// block = 4 waves (mg) x M_=4 m, one d-half, one batch.
// x rows br=0..111 (abs row R0+br, R0=32mb-40), 1KB each.
//   x ring: 64 rows (slot br&63), chunks of 8 rows.
//   filt ring: 12 rows (slot fr%12, compile-time for reads), 4-row chunks.
// Phase p (0..9) = steps t=4p..4p+3; reads x chunks p..p+4, filt rows
// 4p+2..4p+9 (ldsF(t+2), t<=4p+3). Stage at phase-p start (p<=8):
//   x rows 8p+40+2mg, +1 (chunk p+5; slots disjoint from read chunks;
//   overwrites chunk p-3, dead 3 barriers) — running ptr pxs += 8*D_,
//   slot xslot=(40+2mg+8p)&63 running += 8 (even, pair never wraps).
//   filt row 4p+8+mg (chunk p+2; slot group (p+2)%3 vs reads p,p+1;
//   guard fr<=40) — running ptr pf += 4*D_, fslot += 4 wrap -12.
// DMA drained by end-of-phase barrier; first read one phase later.
// Prologue: x rows 0..39 + filt rows 0..7. Tail: t=40 register-only.
//
// Step semantics (refcheck'd R4..R12): t<=20: ae+=f[t]*wE, ao+=f[t]*wO;
// t>=21 swapped. E push br=8mg+2t+8; O push +1 (t<20) / -1 (t>20);
// O holds at t=20.
//
// Spill ledger: clean={R4@128 simple body, R7/R9@256}; spill={R2 no-
// unroll, R3@~170, R8@128 index-hoist, R10/R11 512thr pin128, R12@256
// runtime-ring}. R13 bets running pointers fit 128. Tell: FETCH>=400MB.

#define B_ 32
#define T_ 2000
#define D_ 512
#define S_ 1000   // T/2
#define M_ 4      // m-positions per thread (=> 8 output rows)

#define FR_ 12                    // filt ring rows
#define FOFF 0                    // filt ring base (floats)
#define XOFF (FR_ * 256)          // x ring base (floats)
#define LDS_FLOATS (XOFF + 64 * 256)   // 76 KiB total

__device__ __forceinline__ float4 zf4() {
    float4 z; z.x = 0.f; z.y = 0.f; z.z = 0.f; z.w = 0.f; return z;
}

__device__ __forceinline__ void fma4(float4& a, const float4 f, const float4 w) {
    a.x = fmaf(f.x, w.x, a.x);
    a.y = fmaf(f.y, w.y, a.y);
    a.z = fmaf(f.z, w.z, a.z);
    a.w = fmaf(f.w, w.w, a.w);
}

// Async global->LDS DMA: 16B/lane x 64 lanes = one 1KB row per call.
__device__ __forceinline__ void gload_lds16(const float* g, float* l) {
    __builtin_amdgcn_global_load_lds(
        (const __attribute__((address_space(1))) void*)g,
        (__attribute__((address_space(3))) void*)l,
        16, 0, 0);
}

template<bool CHK>
__device__ __forceinline__ void fsmn_body(float* __restrict__ lds,
                                          const float* __restrict__ xb,
                                          const float* __restrict__ fb,
                                          float* __restrict__ ob,
                                          int m0, int R0, int lane, int mg)
{
    // ---- LDS read helpers (all slot math compile-time foldable) ----
    auto ldrow = [&](int br) -> float4 {              // x ring, br = const + 8mg
        return *(const float4*)(lds + XOFF + ((br & 63) << 8) + lane * 4);
    };
    auto ldsF = [&](int t) -> float4 {                // filt ring, t compile-time
        return *(const float4*)(lds + FOFF + ((t % FR_) << 8) + lane * 4);
    };
    // guarded single-row stage (slot precomputed by caller)
    auto stg = [&](const float* g, int slot, int row) {
        float* l = lds + XOFF + (slot << 8);
        if (!CHK || (unsigned)row < (unsigned)T_) gload_lds16(g, l);
        else *(float4*)(l + lane * 4) = zf4();        // zero-fill pad rows
    };

    // ---- Prologue: filt rows 0..7 + x rows 0..39 (slot == row index) ----
#pragma unroll
    for (int k = 0; k < 2; ++k) {
        const int fr = 4 * k + mg;                    // <= 7, always valid
        gload_lds16(fb + (size_t)fr * D_, lds + FOFF + (fr << 8));
    }
#pragma unroll
    for (int k = 0; k < 10; ++k) {
        const int r = 4 * k + mg;                     // 0..39
        stg(xb + (size_t)(R0 + r) * D_, r, R0 + r);
    }
    __syncthreads();                                  // all prologue DMA done

    // ---- Init windows (rows <= 31) + filter queue ----
    float4 wE[M_], wO[M_], ae[M_], ao[M_];
#pragma unroll
    for (int m = 0; m < M_; ++m) {
        wE[m] = ldrow(8 * mg + 2 * m);
        wO[m] = ldrow(8 * mg + 2 * m + 1);
        ae[m] = zf4(); ao[m] = zf4();
    }
    float4 qF0 = ldsF(0), qF1 = ldsF(1);              // dist-2 LDS queue

    // ---- One step (tap filt[t]); t compile-time under unroll ----
    auto dostep = [&](int t) {
        const float4 fv = qF0;
        qF0 = qF1;
        qF1 = (t + 2 <= 40) ? ldsF(t + 2) : zf4();
        if (t <= 20) {
#pragma unroll
            for (int m = 0; m < M_; ++m) { fma4(ae[m], fv, wE[m]); fma4(ao[m], fv, wO[m]); }
        } else {
#pragma unroll
            for (int m = 0; m < M_; ++m) { fma4(ao[m], fv, wE[m]); fma4(ae[m], fv, wO[m]); }
        }
        if (t < 40) {
#pragma unroll
            for (int m = 0; m < M_ - 1; ++m) wE[m] = wE[m + 1];
            wE[M_ - 1] = ldrow(8 * mg + 2 * t + 8);
            if (t != 20) {                            // O holds at junction
#pragma unroll
                for (int m = 0; m < M_ - 1; ++m) wO[m] = wO[m + 1];
                wO[M_ - 1] = ldrow(8 * mg + 2 * t + 8 + ((t < 20) ? 1 : -1));
            }
        }
    };

    // ---- Running staging state (the anti-hoist fix) ----
    const float* pxs = xb + (size_t)(R0 + 40 + 2 * mg) * D_;  // x stage ptr
    const float* pf  = fb + (size_t)(8 + mg) * D_;            // filt stage ptr
    int xslot = 40 + 2 * mg;               // (40+2mg+8p)&63, even -> pair safe
    int fslot = 8 + mg;                    // (8+mg+4p)%12
    int xrow  = R0 + 40 + 2 * mg;          // guard only (CHK)
    int frow  = 8 + mg;                    // guard fr<=40

    // ---- Phases p=0..9 (4 steps each), then register-only tail t=40 ----
#pragma unroll
    for (int p = 0; p < 10; ++p) {
        if (p <= 8) {                                 // stage one phase ahead
            stg(pxs,      xslot,     xrow);           // x chunk p+5, row A
            stg(pxs + D_, xslot + 1, xrow + 1);       // x chunk p+5, row B
            if (frow <= 40)                           // filt chunk p+2
                gload_lds16(pf, lds + FOFF + (fslot << 8));
            pxs += 8 * (size_t)D_;  xslot = (xslot + 8) & 63;  xrow += 8;
            pf  += 4 * (size_t)D_;  fslot += 4; if (fslot >= FR_) fslot -= FR_;
            frow += 4;
        }
#pragma unroll
        for (int t = 4 * p; t < 4 * p + 4; ++t) dostep(t);
        if (p < 9) __syncthreads();                   // drain DMA + fence reuse
    }
    dostep(40);

    // ---- Store 2*M_ output rows (coalesced float4 across 64 lanes) ----
#pragma unroll
    for (int m = 0; m < M_; ++m) {
        if (!CHK || (m0 + m) < S_) {
            *(float4*)(ob + (size_t)(2 * (m0 + m))     * D_) = ae[m];
            *(float4*)(ob + (size_t)(2 * (m0 + m) + 1) * D_) = ao[m];
        }
    }
}

__global__ __launch_bounds__(256, 2) void fsmn_kernel(
    const float* __restrict__ x, const float* __restrict__ filt,
    float* __restrict__ out)
{
    __shared__ float lds[LDS_FLOATS];      // 76 KiB: filt ring 12KB + x ring 64KB

    const int lane = threadIdx.x;          // 0..63
    const int mg   = threadIdx.y;          // 0..3 : m-group (one wave each)

    // XCD-chunked swizzle: 4032 blocks = 8 XCDs x 504 (bijective).
    const int bid  = blockIdx.x;
    const int xcd  = bid & 7;
    const int slot = bid >> 3;
    const int n    = xcd * 504 + slot;
    const int mb   = n % 63;               // 0..62 : m-block (16 m each)
    const int rest = n / 63;
    const int dh   = rest & 1;             // d-half
    const int b    = rest >> 1;            // batch

    const int m0b = mb * 16;
    const int m0  = m0b + mg * M_;
    const int d   = (dh * 64 + lane) * 4;
    const float* xb = x + (size_t)b * T_ * D_ + d;
    const float* fb = filt + d;
    float*       ob = out + (size_t)b * T_ * D_ + d;
    const int R0  = 2 * m0b - 40;          // x row of block-row 0

    // Interior iff staged rows br=0..111 and all stores valid: mb in [2,60].
    // No early-return — all 256 threads reach every barrier.
    if (mb >= 2 && mb <= 60) fsmn_body<false>(lds, xb, fb, ob, m0, R0, lane, mg);
    else                     fsmn_body<true >(lds, xb, fb, ob, m0, R0, lane, mg);
}

extern "C" void kernel_launch(void* const* d_in, const int* in_sizes, int n_in,
                              void* d_out, int out_size, void* d_ws, size_t ws_size,
                              hipStream_t stream) {
    const float* x    = (const float*)d_in[0];
    const float* filt = (const float*)d_in[1];
    float*       out  = (float*)d_out;

    dim3 block(64, 4, 1);
    // 63 m-blocks x 2 d-halves x 32 batches = 4032 blocks.
    dim3 grid(4032, 1, 1);
    hipLaunchKernelGGL(fsmn_kernel, grid, block, 0, stream, x, filt, out);
}